// Round 3
// baseline (14776.601 us; speedup 1.0000x reference)
//
#include <hip/hip_runtime.h>
#include <math.h>

constexpr int NB = 256, NT = 64, DS = 128, DA = 32, DB = 1024, DH = 1024, DE = 1024;
constexpr float MIN_STD = 0.1f;

constexpr size_t OUT_PS  = (size_t)NT * NB * DB;
constexpr size_t OUT_PM  = OUT_PS  + (size_t)NT * NB * DS;
constexpr size_t OUT_PSD = OUT_PM  + (size_t)NT * NB * DS;
constexpr size_t OUT_QS  = OUT_PSD + (size_t)NT * NB * DS;
constexpr size_t OUT_QM  = OUT_QS  + (size_t)NT * NB * DS;
constexpr size_t OUT_QSD = OUT_QM  + (size_t)NT * NB * DS;

typedef __attribute__((ext_vector_type(8))) short bf8_t;
typedef __attribute__((ext_vector_type(4))) float f4_t;
#define MFMA16(a, b, c) __builtin_amdgcn_mfma_f32_16x16x32_bf16((a), (b), (c), 0, 0, 0)

__device__ __forceinline__ short f2bf(float f) {
    union { float f; unsigned u; } v; v.f = f;
    unsigned r = v.u + 0x7FFF + ((v.u >> 16) & 1);
    return (short)(r >> 16);
}
__device__ __forceinline__ unsigned pack2(float a, float b) {
    return ((unsigned)(unsigned short)f2bf(a)) | (((unsigned)(unsigned short)f2bf(b)) << 16);
}
__device__ __forceinline__ float sigm(float x) { return 1.0f / (1.0f + __expf(-x)); }

// Grid barrier: 8 striped counters (64B apart). Block adds to stripe bid&7;
// threads 0..7 each poll one stripe until it reaches 32*barrier_index.
__device__ __forceinline__ void gbar(unsigned* cnt, unsigned tgt32) {
    __syncthreads();
    const int tx = threadIdx.x;
    if (tx == 0) {
        __threadfence();
        __hip_atomic_fetch_add(&cnt[(blockIdx.x & 7) * 16], 1u,
                               __ATOMIC_RELEASE, __HIP_MEMORY_SCOPE_AGENT);
    }
    if (tx < 8) {
        unsigned spins = 0;
        while (__hip_atomic_load(&cnt[tx * 16], __ATOMIC_ACQUIRE,
                                 __HIP_MEMORY_SCOPE_AGENT) < tgt32) {
            __builtin_amdgcn_s_sleep(2);
            if (++spins > 20000000u) break;   // safety valve: fail, don't hang
        }
    }
    if (tx == 0) __threadfence();
    __syncthreads();
}

__global__ __launch_bounds__(256) void rssm_persist(
    const float* __restrict__ prev_state, const float* __restrict__ actions,
    const float* __restrict__ prev_belief, const float* __restrict__ observations,
    const float* __restrict__ nonterm,
    const float* __restrict__ prior_noise, const float* __restrict__ post_noise,
    const float* __restrict__ W_sa, const float* __restrict__ b_sa,
    const float* __restrict__ W_ih, const float* __restrict__ W_hh,
    const float* __restrict__ b_ih, const float* __restrict__ b_hh,
    const float* __restrict__ W_bp, const float* __restrict__ b_bp,
    const float* __restrict__ W_sp, const float* __restrict__ b_sp,
    const float* __restrict__ W_bq, const float* __restrict__ b_bq,
    const float* __restrict__ W_sq, const float* __restrict__ b_sq,
    float* __restrict__ out, unsigned* __restrict__ cnt, short* __restrict__ wsh)
{
    __shared__ __align__(16) char smem[28672];

    const int bid = blockIdx.x;
    const int tx  = threadIdx.x;
    const int wv  = tx >> 6, lane = tx & 63;

    // workspace layout (shorts)
    short* Wih_bf = wsh;
    short* Whh_bf = Wih_bf + (size_t)3145728;
    short* Wbp_bf = Whh_bf + (size_t)3145728;
    short* Wbq_bf = Wbp_bf + (size_t)1048576;
    short* Wsp_bf = Wbq_bf + (size_t)2097152;
    short* Wsq_bf = Wsp_bf + (size_t)262144;
    short* Ax     = Wsq_bf + (size_t)262144;   // x bf16 [256][1024]
    short* nbb    = Ax     + (size_t)262144;   // nb bf16 [256][1024]
    short* hpb    = nbb    + (size_t)262144;   // hp bf16
    short* hqb    = hpb    + (size_t)262144;   // hq bf16

    float* beliefs = out;
    float* o_ps  = out + OUT_PS;
    float* o_pm  = out + OUT_PM;
    float* o_psd = out + OUT_PSD;
    float* o_qs  = out + OUT_QS;
    float* o_qm  = out + OUT_QM;
    float* o_qsd = out + OUT_QSD;

    // ---- init: convert weights to bf16 (grid-stride) ----
    {
        const int gtid = bid * 256 + tx;
        auto cvt = [&](const float* s, short* d, int nchunk) {
            const float4* s4 = (const float4*)s;
            bf8_t* d8 = (bf8_t*)d;
            for (int i = gtid; i < nchunk; i += 65536) {
                float4 a = s4[2 * i], b = s4[2 * i + 1];
                bf8_t v;
                v[0]=f2bf(a.x); v[1]=f2bf(a.y); v[2]=f2bf(a.z); v[3]=f2bf(a.w);
                v[4]=f2bf(b.x); v[5]=f2bf(b.y); v[6]=f2bf(b.z); v[7]=f2bf(b.w);
                d8[i] = v;
            }
        };
        cvt(W_ih, Wih_bf, 393216);
        cvt(W_hh, Whh_bf, 393216);
        cvt(W_bp, Wbp_bf, 131072);
        cvt(W_bq, Wbq_bf, 262144);
        cvt(W_sp, Wsp_bf, 32768);
        cvt(W_sq, Wsq_bf, 32768);
    }
    unsigned bar = 32;
    gbar(cnt, bar); bar += 32;

    const bf8_t* Ax8 = (const bf8_t*)Ax;
    const bf8_t* nb8 = (const bf8_t*)nbb;
    const bf8_t* Wi8 = (const bf8_t*)Wih_bf;
    const bf8_t* Wh8 = (const bf8_t*)Whh_bf;

    for (int t = 0; t < NT; ++t) {
        // ================= Phase A: x = relu([s*nt | a] @ W_sa^T + b_sa) ====
        {
            float* sa   = (float*)smem;          // [16][160]
            float* xbuf = sa + 2560;             // [16][64]
            const int bt = bid >> 4;             // 16 b-tiles of 16
            const int j0 = (bid & 15) * 64;
            const int b0 = bt * 16;
            for (int i = tx; i < 2560; i += 256) {
                int r = i / 160, k = i - r * 160;
                int b = b0 + r;
                float v;
                if (k < DS) {
                    float s = (t == 0) ? prev_state[b * DS + k]
                                       : o_qs[((size_t)(t - 1) * NB + b) * DS + k];
                    float ntv = (t == 0) ? 1.0f : nonterm[(t - 1) * NB + b];
                    v = s * ntv;
                } else {
                    v = actions[((size_t)t * NB + b) * DA + (k - DS)];
                }
                sa[i] = v;
            }
            __syncthreads();
            const int j = j0 + (tx & 63);
            const int bset = tx >> 6;
            const float4* w4 = (const float4*)(W_sa + (size_t)j * 160);
            float bj = b_sa[j];
            float acc[4] = {bj, bj, bj, bj};
            for (int k4 = 0; k4 < 40; ++k4) {
                float4 w = w4[k4];
                #pragma unroll
                for (int m = 0; m < 4; ++m) {
                    const float* sr = sa + (bset * 4 + m) * 160 + k4 * 4;
                    acc[m] = fmaf(w.x, sr[0], fmaf(w.y, sr[1],
                             fmaf(w.z, sr[2], fmaf(w.w, sr[3], acc[m]))));
                }
            }
            #pragma unroll
            for (int m = 0; m < 4; ++m)
                xbuf[(bset * 4 + m) * 64 + (tx & 63)] = fmaxf(acc[m], 0.0f);
            __syncthreads();
            {
                int r = tx >> 4, p = tx & 15;
                float* src = xbuf + r * 64 + p * 4;
                uint2 v; v.x = pack2(src[0], src[1]); v.y = pack2(src[2], src[3]);
                *(uint2*)(Ax + (size_t)(b0 + r) * DB + j0 + p * 4) = v;
            }
        }
        gbar(cnt, bar); bar += 32;

        // ================= Phase B: GRU (6 gate GEMMs + gate math) ==========
        {
            bf8_t* sAx = (bf8_t*)smem;           // 64x8  (8KB)
            bf8_t* sAh = sAx + 512;              // 8KB
            bf8_t* sBw = sAh + 512;              // 6x16x8 (12KB)
            const int b0 = (bid >> 6) * 64;      // 4 b-tiles
            const int j0 = (bid & 63) * 16;      // 64 j-tiles
            const int wg = wv & 1, wm = wv >> 1;
            const float* belp = (t == 0) ? prev_belief : beliefs + (size_t)(t - 1) * NB * DB;

            f4_t acc[3][2];
            #pragma unroll
            for (int g = 0; g < 3; ++g) { acc[g][0] = (f4_t)0.0f; acc[g][1] = (f4_t)0.0f; }

            for (int kt = 0; kt < DB; kt += 64) {
                #pragma unroll
                for (int i = 0; i < 2; ++i) {
                    int c = tx + i * 256;
                    int row = c >> 3, ch = c & 7;
                    int b = b0 + row;
                    sAx[row * 8 + (ch ^ (row & 7))] = Ax8[(size_t)b * 128 + (kt >> 3) + ch];
                    const float4* p4 = (const float4*)(belp + (size_t)b * DB + kt + ch * 8);
                    float4 f0 = p4[0], f1 = p4[1];
                    float ntv = (t == 0) ? 1.0f : nonterm[(t - 1) * NB + b];
                    bf8_t v;
                    v[0]=f2bf(f0.x*ntv); v[1]=f2bf(f0.y*ntv); v[2]=f2bf(f0.z*ntv); v[3]=f2bf(f0.w*ntv);
                    v[4]=f2bf(f1.x*ntv); v[5]=f2bf(f1.y*ntv); v[6]=f2bf(f1.z*ntv); v[7]=f2bf(f1.w*ntv);
                    sAh[row * 8 + (ch ^ (row & 7))] = v;
                }
                #pragma unroll
                for (int i = 0; i < 3; ++i) {
                    int c = tx + i * 256;
                    int g = c >> 7;
                    int r = (c >> 3) & 15, ch = c & 7;
                    const bf8_t* W = (g < 3) ? Wi8 : Wh8;
                    int gm3 = (g >= 3) ? g - 3 : g;
                    int grow = gm3 * DB + j0 + r;
                    sBw[(g * 16 + r) * 8 + (ch ^ (r & 7))] = W[(size_t)grow * 128 + (kt >> 3) + ch];
                }
                __syncthreads();
                #pragma unroll
                for (int ks = 0; ks < 2; ++ks) {
                    int ch = ks * 4 + (lane >> 4);
                    bf8_t a[2], bw[3];
                    #pragma unroll
                    for (int mi = 0; mi < 2; ++mi) {
                        int row = wm * 32 + mi * 16 + (lane & 15);
                        a[mi] = wg ? sAh[row * 8 + (ch ^ (row & 7))]
                                   : sAx[row * 8 + (ch ^ (row & 7))];
                    }
                    #pragma unroll
                    for (int g = 0; g < 3; ++g) {
                        int r = lane & 15;
                        bw[g] = sBw[((wg * 3 + g) * 16 + r) * 8 + (ch ^ (r & 7))];
                    }
                    #pragma unroll
                    for (int g = 0; g < 3; ++g)
                        #pragma unroll
                        for (int mi = 0; mi < 2; ++mi)
                            acc[g][mi] = MFMA16(a[mi], bw[g], acc[g][mi]);
                }
                __syncthreads();
            }
            // epilogue: exchange gh accs, gate math, coalesced stores
            float* exg = (float*)smem;           // [3][64][16] = 12KB
            float* exn = exg + 3072;             // [64][16]   = 4KB
            if (wg == 1) {
                #pragma unroll
                for (int g = 0; g < 3; ++g)
                    #pragma unroll
                    for (int mi = 0; mi < 2; ++mi)
                        #pragma unroll
                        for (int r = 0; r < 4; ++r) {
                            int bl = wm * 32 + mi * 16 + (lane >> 4) * 4 + r;
                            exg[(g * 64 + bl) * 16 + (lane & 15)] = acc[g][mi][r];
                        }
            }
            __syncthreads();
            if (wg == 0) {
                int jl = lane & 15, j = j0 + jl;
                float bir = b_ih[j], biz = b_ih[DB + j], bin = b_ih[2 * DB + j];
                float bhr = b_hh[j], bhz = b_hh[DB + j], bhn = b_hh[2 * DB + j];
                #pragma unroll
                for (int mi = 0; mi < 2; ++mi)
                    #pragma unroll
                    for (int r = 0; r < 4; ++r) {
                        int bl = wm * 32 + mi * 16 + (lane >> 4) * 4 + r;
                        int b = b0 + bl;
                        float ntv = (t == 0) ? 1.0f : nonterm[(t - 1) * NB + b];
                        float h = belp[(size_t)b * DB + j] * ntv;
                        float rr = sigm(acc[0][mi][r] + bir + exg[(0 * 64 + bl) * 16 + jl] + bhr);
                        float zz = sigm(acc[1][mi][r] + biz + exg[(1 * 64 + bl) * 16 + jl] + bhz);
                        float nn = tanhf(acc[2][mi][r] + bin + rr * (exg[(2 * 64 + bl) * 16 + jl] + bhn));
                        exn[bl * 16 + jl] = (1.0f - zz) * nn + zz * h;
                    }
            }
            __syncthreads();
            {
                int bl = tx >> 2, p = tx & 3;
                float* src = exn + bl * 16 + p * 4;
                float4 v = {src[0], src[1], src[2], src[3]};
                int b = b0 + bl;
                *(float4*)(beliefs + (size_t)t * NB * DB + (size_t)b * DB + j0 + p * 4) = v;
                uint2 u; u.x = pack2(v.x, v.y); u.y = pack2(v.z, v.w);
                *(uint2*)(nbb + (size_t)b * DB + j0 + p * 4) = u;
            }
        }
        gbar(cnt, bar); bar += 32;

        // ================= Phase C: hp / hq hidden layers ===================
        {
            if (bid < 64) {          // hp: 64x64 tile, K=1024
                bf8_t* sA = (bf8_t*)smem;
                bf8_t* sB = sA + 512;
                const int b0 = (bid >> 4) * 64, j0 = (bid & 15) * 64;
                const int wm = wv & 1, wn = wv >> 1;
                const bf8_t* Wp8 = (const bf8_t*)Wbp_bf;
                f4_t acc[2][2];
                acc[0][0] = (f4_t)0.0f; acc[0][1] = (f4_t)0.0f;
                acc[1][0] = (f4_t)0.0f; acc[1][1] = (f4_t)0.0f;
                for (int kt = 0; kt < DB; kt += 64) {
                    #pragma unroll
                    for (int i = 0; i < 2; ++i) {
                        int c = tx + i * 256;
                        int row = c >> 3, ch = c & 7;
                        sA[row * 8 + (ch ^ (row & 7))] = nb8[(size_t)(b0 + row) * 128 + (kt >> 3) + ch];
                        sB[row * 8 + (ch ^ (row & 7))] = Wp8[(size_t)(j0 + row) * 128 + (kt >> 3) + ch];
                    }
                    __syncthreads();
                    #pragma unroll
                    for (int ks = 0; ks < 2; ++ks) {
                        int ch = ks * 4 + (lane >> 4);
                        bf8_t a[2], b[2];
                        #pragma unroll
                        for (int mi = 0; mi < 2; ++mi) {
                            int row = wm * 32 + mi * 16 + (lane & 15);
                            a[mi] = sA[row * 8 + (ch ^ (row & 7))];
                        }
                        #pragma unroll
                        for (int ni = 0; ni < 2; ++ni) {
                            int row = wn * 32 + ni * 16 + (lane & 15);
                            b[ni] = sB[row * 8 + (ch ^ (row & 7))];
                        }
                        #pragma unroll
                        for (int mi = 0; mi < 2; ++mi)
                            #pragma unroll
                            for (int ni = 0; ni < 2; ++ni)
                                acc[mi][ni] = MFMA16(a[mi], b[ni], acc[mi][ni]);
                    }
                    __syncthreads();
                }
                float* ebuf = (float*)smem;      // [64][64]
                #pragma unroll
                for (int mi = 0; mi < 2; ++mi)
                    #pragma unroll
                    for (int ni = 0; ni < 2; ++ni)
                        #pragma unroll
                        for (int r = 0; r < 4; ++r) {
                            int row = wm * 32 + mi * 16 + (lane >> 4) * 4 + r;
                            int col = wn * 32 + ni * 16 + (lane & 15);
                            ebuf[row * 64 + col] = fmaxf(acc[mi][ni][r] + b_bp[j0 + col], 0.0f);
                        }
                __syncthreads();
                {
                    int bl = tx >> 2, p = tx & 3;
                    float* src = ebuf + bl * 64 + p * 16;
                    short* dst = hpb + (size_t)(b0 + bl) * DH + j0 + p * 16;
                    #pragma unroll
                    for (int q = 0; q < 4; ++q) {
                        uint2 u; u.x = pack2(src[q*4], src[q*4+1]); u.y = pack2(src[q*4+2], src[q*4+3]);
                        *(uint2*)(dst + q * 4) = u;
                    }
                }
            } else if (bid < 192) {  // hq: 64x32 tile, K=2048
                bf8_t* sA = (bf8_t*)smem;
                bf8_t* sB = sA + 512;
                const int q = bid - 64;
                const int b0 = (q >> 5) * 64, j0 = (q & 31) * 32;
                const int wm = wv & 1, wn = wv >> 1;
                const bf8_t* Wq8 = (const bf8_t*)Wbq_bf;
                const float* obs_t = observations + (size_t)t * NB * DE;
                f4_t acc[2];
                acc[0] = (f4_t)0.0f; acc[1] = (f4_t)0.0f;
                for (int kt = 0; kt < DB + DE; kt += 64) {
                    #pragma unroll
                    for (int i = 0; i < 2; ++i) {
                        int c = tx + i * 256;
                        int row = c >> 3, ch = c & 7;
                        int b = b0 + row;
                        bf8_t v;
                        if (kt < DB) {
                            v = nb8[(size_t)b * 128 + (kt >> 3) + ch];
                        } else {
                            const float4* p4 = (const float4*)(obs_t + (size_t)b * DE + (kt - DB) + ch * 8);
                            float4 f0 = p4[0], f1 = p4[1];
                            v[0]=f2bf(f0.x); v[1]=f2bf(f0.y); v[2]=f2bf(f0.z); v[3]=f2bf(f0.w);
                            v[4]=f2bf(f1.x); v[5]=f2bf(f1.y); v[6]=f2bf(f1.z); v[7]=f2bf(f1.w);
                        }
                        sA[row * 8 + (ch ^ (row & 7))] = v;
                    }
                    {
                        int row = tx >> 3, ch = tx & 7;   // 32 rows
                        sB[row * 8 + (ch ^ (row & 7))] = Wq8[(size_t)(j0 + row) * 256 + (kt >> 3) + ch];
                    }
                    __syncthreads();
                    #pragma unroll
                    for (int ks = 0; ks < 2; ++ks) {
                        int ch = ks * 4 + (lane >> 4);
                        bf8_t a[2], b;
                        #pragma unroll
                        for (int mi = 0; mi < 2; ++mi) {
                            int row = wm * 32 + mi * 16 + (lane & 15);
                            a[mi] = sA[row * 8 + (ch ^ (row & 7))];
                        }
                        {
                            int row = wn * 16 + (lane & 15);
                            b = sB[row * 8 + (ch ^ (row & 7))];
                        }
                        acc[0] = MFMA16(a[0], b, acc[0]);
                        acc[1] = MFMA16(a[1], b, acc[1]);
                    }
                    __syncthreads();
                }
                float* ebuf = (float*)smem;      // [64][32]
                #pragma unroll
                for (int mi = 0; mi < 2; ++mi)
                    #pragma unroll
                    for (int r = 0; r < 4; ++r) {
                        int row = wm * 32 + mi * 16 + (lane >> 4) * 4 + r;
                        int col = wn * 16 + (lane & 15);
                        ebuf[row * 32 + col] = fmaxf(acc[mi][r] + b_bq[j0 + col], 0.0f);
                    }
                __syncthreads();
                {
                    int bl = tx >> 2, p = tx & 3;
                    float* src = ebuf + bl * 32 + p * 8;
                    short* dst = hqb + (size_t)(b0 + bl) * DH + j0 + p * 8;
                    #pragma unroll
                    for (int q2 = 0; q2 < 2; ++q2) {
                        uint2 u; u.x = pack2(src[q2*4], src[q2*4+1]); u.y = pack2(src[q2*4+2], src[q2*4+3]);
                        *(uint2*)(dst + q2 * 4) = u;
                    }
                }
            }
        }
        gbar(cnt, bar); bar += 32;

        // ================= Phase D: head outputs + sampling =================
        {
            if (bid < 64) {
                const int head = bid >> 5;
                const int q = bid & 31;
                const int b0 = (q >> 3) * 64, i0 = (q & 7) * 16;
                const bf8_t* A8 = (const bf8_t*)(head ? hqb : hpb);
                const bf8_t* W8 = (const bf8_t*)(head ? Wsq_bf : Wsp_bf);
                bf8_t* sA = (bf8_t*)smem;
                bf8_t* sB = sA + 512;
                const int wm = wv & 1, wn = wv >> 1;
                f4_t acc[2];
                acc[0] = (f4_t)0.0f; acc[1] = (f4_t)0.0f;
                for (int kt = 0; kt < DH; kt += 64) {
                    #pragma unroll
                    for (int i = 0; i < 2; ++i) {
                        int c = tx + i * 256;
                        int row = c >> 3, ch = c & 7;
                        sA[row * 8 + (ch ^ (row & 7))] = A8[(size_t)(b0 + row) * 128 + (kt >> 3) + ch];
                    }
                    {
                        int row = tx >> 3, ch = tx & 7;   // 32 rows: 16 mean + 16 sd
                        int wr = (row < 16) ? (i0 + row) : (128 + i0 + (row - 16));
                        sB[row * 8 + (ch ^ (row & 7))] = W8[(size_t)wr * 128 + (kt >> 3) + ch];
                    }
                    __syncthreads();
                    #pragma unroll
                    for (int ks = 0; ks < 2; ++ks) {
                        int ch = ks * 4 + (lane >> 4);
                        bf8_t a[2], b;
                        #pragma unroll
                        for (int mi = 0; mi < 2; ++mi) {
                            int row = wm * 32 + mi * 16 + (lane & 15);
                            a[mi] = sA[row * 8 + (ch ^ (row & 7))];
                        }
                        {
                            int row = wn * 16 + (lane & 15);
                            b = sB[row * 8 + (ch ^ (row & 7))];
                        }
                        acc[0] = MFMA16(a[0], b, acc[0]);
                        acc[1] = MFMA16(a[1], b, acc[1]);
                    }
                    __syncthreads();
                }
                float* ebuf = (float*)smem;      // [64][32]
                #pragma unroll
                for (int mi = 0; mi < 2; ++mi)
                    #pragma unroll
                    for (int r = 0; r < 4; ++r) {
                        int row = wm * 32 + mi * 16 + (lane >> 4) * 4 + r;
                        int col = wn * 16 + (lane & 15);
                        ebuf[row * 32 + col] = acc[mi][r];
                    }
                __syncthreads();
                {
                    const float* bias  = head ? b_sq : b_sp;
                    const float* noise = head ? post_noise : prior_noise;
                    float* om  = head ? o_qm  : o_pm;
                    float* osd = head ? o_qsd : o_psd;
                    float* os  = head ? o_qs  : o_ps;
                    int bl = tx >> 2, p = tx & 3;
                    int b = b0 + bl;
                    float4 vm, vs, vx;
                    #pragma unroll
                    for (int k = 0; k < 4; ++k) {
                        int i = p * 4 + k;
                        float m_ = ebuf[bl * 32 + i] + bias[i0 + i];
                        float sraw = ebuf[bl * 32 + 16 + i] + bias[128 + i0 + i];
                        float sd = log1pf(__expf(-fabsf(sraw))) + fmaxf(sraw, 0.0f) + MIN_STD;
                        float n_ = noise[((size_t)t * NB + b) * DS + i0 + i];
                        ((float*)&vm)[k] = m_;
                        ((float*)&vs)[k] = sd;
                        ((float*)&vx)[k] = fmaf(sd, n_, m_);
                    }
                    size_t off = ((size_t)t * NB + b) * DS + i0 + p * 4;
                    *(float4*)(om + off)  = vm;
                    *(float4*)(osd + off) = vs;
                    *(float4*)(os + off)  = vx;
                }
            }
        }
        gbar(cnt, bar); bar += 32;
    }
}

extern "C" void kernel_launch(void* const* d_in, const int* in_sizes, int n_in,
                              void* d_out, int out_size, void* d_ws, size_t ws_size,
                              hipStream_t stream)
{
    const float* prev_state   = (const float*)d_in[0];
    const float* actions      = (const float*)d_in[1];
    const float* prev_belief  = (const float*)d_in[2];
    const float* observations = (const float*)d_in[3];
    const float* nonterm      = (const float*)d_in[4];
    const float* prior_noise  = (const float*)d_in[5];
    const float* post_noise   = (const float*)d_in[6];
    const float* W_sa = (const float*)d_in[7];
    const float* b_sa = (const float*)d_in[8];
    const float* W_ih = (const float*)d_in[9];
    const float* W_hh = (const float*)d_in[10];
    const float* b_ih = (const float*)d_in[11];
    const float* b_hh = (const float*)d_in[12];
    const float* W_bp = (const float*)d_in[13];
    const float* b_bp = (const float*)d_in[14];
    const float* W_sp = (const float*)d_in[15];
    const float* b_sp = (const float*)d_in[16];
    const float* W_bq = (const float*)d_in[17];
    const float* b_bq = (const float*)d_in[18];
    const float* W_sq = (const float*)d_in[19];
    const float* b_sq = (const float*)d_in[20];

    // ws: [0,512) barrier counters, then bf16 arrays
    hipMemsetAsync(d_ws, 0, 512, stream);
    unsigned* cnt = (unsigned*)d_ws;
    short* wsh = (short*)((char*)d_ws + 512);

    rssm_persist<<<256, 256, 0, stream>>>(
        prev_state, actions, prev_belief, observations, nonterm,
        prior_noise, post_noise,
        W_sa, b_sa, W_ih, W_hh, b_ih, b_hh,
        W_bp, b_bp, W_sp, b_sp, W_bq, b_bq, W_sq, b_sq,
        (float*)d_out, cnt, wsh);
}

// Round 4
// 5641.414 us; speedup vs baseline: 2.6193x; 2.6193x over previous
//
#include <hip/hip_runtime.h>
#include <math.h>

constexpr int NB = 256, NT = 64, DS = 128, DA = 32, DB = 1024, DH = 1024, DE = 1024;
constexpr float MIN_STD = 0.1f;

constexpr size_t OUT_PS  = (size_t)NT * NB * DB;
constexpr size_t OUT_PM  = OUT_PS  + (size_t)NT * NB * DS;
constexpr size_t OUT_PSD = OUT_PM  + (size_t)NT * NB * DS;
constexpr size_t OUT_QS  = OUT_PSD + (size_t)NT * NB * DS;
constexpr size_t OUT_QM  = OUT_QS  + (size_t)NT * NB * DS;
constexpr size_t OUT_QSD = OUT_QM  + (size_t)NT * NB * DS;

typedef __attribute__((ext_vector_type(8))) short bf8_t;
typedef __attribute__((ext_vector_type(4))) float f4_t;
#define MFMA16(a, b, c) __builtin_amdgcn_mfma_f32_16x16x32_bf16((a), (b), (c), 0, 0, 0)

__device__ __forceinline__ short f2bf(float f) {
    union { float f; unsigned u; } v; v.f = f;
    unsigned r = v.u + 0x7FFF + ((v.u >> 16) & 1);
    return (short)(r >> 16);
}
__device__ __forceinline__ unsigned pack2(float a, float b) {
    return ((unsigned)(unsigned short)f2bf(a)) | (((unsigned)(unsigned short)f2bf(b)) << 16);
}
__device__ __forceinline__ float sigm(float x) { return 1.0f / (1.0f + __expf(-x)); }

// ---------------------------------------------------------------------------
// f32 -> bf16 weight conversion
// ---------------------------------------------------------------------------
__global__ __launch_bounds__(256) void k_cvt(const float* __restrict__ src,
                                             short* __restrict__ dst, int n8) {
    int i = blockIdx.x * 256 + threadIdx.x;
    if (i >= n8) return;
    const float4* s4 = (const float4*)src;
    float4 a = s4[i * 2], b = s4[i * 2 + 1];
    bf8_t v;
    v[0]=f2bf(a.x); v[1]=f2bf(a.y); v[2]=f2bf(a.z); v[3]=f2bf(a.w);
    v[4]=f2bf(b.x); v[5]=f2bf(b.y); v[6]=f2bf(b.z); v[7]=f2bf(b.w);
    ((bf8_t*)dst)[i] = v;
}

// ---------------------------------------------------------------------------
// kx: x = relu([s*nt | a] @ W_sa^T + b_sa) -> Ax bf16 [NB][DB]. grid 256.
// ---------------------------------------------------------------------------
__global__ __launch_bounds__(256) void kx(
    const float* __restrict__ st, const float* __restrict__ act,
    const float* __restrict__ ntp,
    const float* __restrict__ W_sa, const float* __restrict__ b_sa,
    short* __restrict__ Ax)
{
    __shared__ float sa[16 * 160];
    __shared__ float xbuf[16 * 64];
    const int tx = threadIdx.x, bid = blockIdx.x;
    const int b0 = (bid >> 4) * 16, j0 = (bid & 15) * 64;
    for (int i = tx; i < 2560; i += 256) {
        int r = i / 160, k = i - r * 160, b = b0 + r;
        float v = (k < DS) ? st[b * DS + k] * (ntp ? ntp[b] : 1.0f)
                           : act[b * DA + (k - DS)];
        sa[i] = v;
    }
    __syncthreads();
    const int j = j0 + (tx & 63);
    const int bset = tx >> 6;
    const float4* w4 = (const float4*)(W_sa + (size_t)j * 160);
    float bj = b_sa[j];
    float acc[4] = {bj, bj, bj, bj};
    for (int k4 = 0; k4 < 40; ++k4) {
        float4 w = w4[k4];
        #pragma unroll
        for (int m = 0; m < 4; ++m) {
            const float* sr = sa + (bset * 4 + m) * 160 + k4 * 4;
            acc[m] = fmaf(w.x, sr[0], fmaf(w.y, sr[1],
                     fmaf(w.z, sr[2], fmaf(w.w, sr[3], acc[m]))));
        }
    }
    #pragma unroll
    for (int m = 0; m < 4; ++m)
        xbuf[(bset * 4 + m) * 64 + (tx & 63)] = fmaxf(acc[m], 0.0f);
    __syncthreads();
    {
        int r = tx >> 4, p = tx & 15;
        float* src = xbuf + r * 64 + p * 4;
        uint2 v; v.x = pack2(src[0], src[1]); v.y = pack2(src[2], src[3]);
        *(uint2*)(Ax + (size_t)(b0 + r) * DB + j0 + p * 4) = v;
    }
}

// ---------------------------------------------------------------------------
// kgru: 6 gate GEMMs + gate math. grid 256 (4 b-tiles x 64 j-tiles of 16).
// Writes beliefs[t] f32 (bel_out) + bf16 copy (nbb).
// ---------------------------------------------------------------------------
__global__ __launch_bounds__(256) void kgru(
    const short* __restrict__ Ax_, const float* __restrict__ belp,
    const float* __restrict__ ntp,
    const short* __restrict__ Wih_bf, const short* __restrict__ Whh_bf,
    const float* __restrict__ b_ih, const float* __restrict__ b_hh,
    float* __restrict__ bel_out, short* __restrict__ nbb)
{
    __shared__ __align__(16) char smem[28672];
    const int bid = blockIdx.x, tx = threadIdx.x;
    const int wv = tx >> 6, lane = tx & 63;
    const bf8_t* Ax8 = (const bf8_t*)Ax_;
    const bf8_t* Wi8 = (const bf8_t*)Wih_bf;
    const bf8_t* Wh8 = (const bf8_t*)Whh_bf;
    bf8_t* sAx = (bf8_t*)smem;
    bf8_t* sAh = sAx + 512;
    bf8_t* sBw = sAh + 512;
    const int b0 = (bid >> 6) * 64, j0 = (bid & 63) * 16;
    const int wg = wv & 1, wm = wv >> 1;

    f4_t acc[3][2];
    #pragma unroll
    for (int g = 0; g < 3; ++g) { acc[g][0] = (f4_t)0.0f; acc[g][1] = (f4_t)0.0f; }

    for (int kt = 0; kt < DB; kt += 64) {
        #pragma unroll
        for (int i = 0; i < 2; ++i) {
            int c = tx + i * 256;
            int row = c >> 3, ch = c & 7, b = b0 + row;
            sAx[row * 8 + (ch ^ (row & 7))] = Ax8[(size_t)b * 128 + (kt >> 3) + ch];
            const float4* p4 = (const float4*)(belp + (size_t)b * DB + kt + ch * 8);
            float4 f0 = p4[0], f1 = p4[1];
            float ntv = ntp ? ntp[b] : 1.0f;
            bf8_t v;
            v[0]=f2bf(f0.x*ntv); v[1]=f2bf(f0.y*ntv); v[2]=f2bf(f0.z*ntv); v[3]=f2bf(f0.w*ntv);
            v[4]=f2bf(f1.x*ntv); v[5]=f2bf(f1.y*ntv); v[6]=f2bf(f1.z*ntv); v[7]=f2bf(f1.w*ntv);
            sAh[row * 8 + (ch ^ (row & 7))] = v;
        }
        #pragma unroll
        for (int i = 0; i < 3; ++i) {
            int c = tx + i * 256;
            int g = c >> 7;
            int r = (c >> 3) & 15, ch = c & 7;
            const bf8_t* W = (g < 3) ? Wi8 : Wh8;
            int gm3 = (g >= 3) ? g - 3 : g;
            int grow = gm3 * DB + j0 + r;
            sBw[(g * 16 + r) * 8 + (ch ^ (r & 7))] = W[(size_t)grow * 128 + (kt >> 3) + ch];
        }
        __syncthreads();
        #pragma unroll
        for (int ks = 0; ks < 2; ++ks) {
            int ch = ks * 4 + (lane >> 4);
            bf8_t a[2], bw[3];
            #pragma unroll
            for (int mi = 0; mi < 2; ++mi) {
                int row = wm * 32 + mi * 16 + (lane & 15);
                a[mi] = wg ? sAh[row * 8 + (ch ^ (row & 7))]
                           : sAx[row * 8 + (ch ^ (row & 7))];
            }
            #pragma unroll
            for (int g = 0; g < 3; ++g) {
                int r = lane & 15;
                bw[g] = sBw[((wg * 3 + g) * 16 + r) * 8 + (ch ^ (r & 7))];
            }
            #pragma unroll
            for (int g = 0; g < 3; ++g)
                #pragma unroll
                for (int mi = 0; mi < 2; ++mi)
                    acc[g][mi] = MFMA16(a[mi], bw[g], acc[g][mi]);
        }
        __syncthreads();
    }

    float* exg = (float*)smem;           // [3][64][16]
    float* exn = exg + 3072;             // [64][16]
    if (wg == 1) {
        #pragma unroll
        for (int g = 0; g < 3; ++g)
            #pragma unroll
            for (int mi = 0; mi < 2; ++mi)
                #pragma unroll
                for (int r = 0; r < 4; ++r) {
                    int bl = wm * 32 + mi * 16 + (lane >> 4) * 4 + r;
                    exg[(g * 64 + bl) * 16 + (lane & 15)] = acc[g][mi][r];
                }
    }
    __syncthreads();
    if (wg == 0) {
        int jl = lane & 15, j = j0 + jl;
        float bir = b_ih[j], biz = b_ih[DB + j], bin = b_ih[2 * DB + j];
        float bhr = b_hh[j], bhz = b_hh[DB + j], bhn = b_hh[2 * DB + j];
        #pragma unroll
        for (int mi = 0; mi < 2; ++mi)
            #pragma unroll
            for (int r = 0; r < 4; ++r) {
                int bl = wm * 32 + mi * 16 + (lane >> 4) * 4 + r;
                int b = b0 + bl;
                float ntv = ntp ? ntp[b] : 1.0f;
                float h = belp[(size_t)b * DB + j] * ntv;
                float rr = sigm(acc[0][mi][r] + bir + exg[(0 * 64 + bl) * 16 + jl] + bhr);
                float zz = sigm(acc[1][mi][r] + biz + exg[(1 * 64 + bl) * 16 + jl] + bhz);
                float nn = tanhf(acc[2][mi][r] + bin + rr * (exg[(2 * 64 + bl) * 16 + jl] + bhn));
                exn[bl * 16 + jl] = (1.0f - zz) * nn + zz * h;
            }
    }
    __syncthreads();
    {
        int bl = tx >> 2, p = tx & 3;
        float* src = exn + bl * 16 + p * 4;
        float4 v = {src[0], src[1], src[2], src[3]};
        int b = b0 + bl;
        *(float4*)(bel_out + (size_t)b * DB + j0 + p * 4) = v;
        uint2 u; u.x = pack2(v.x, v.y); u.y = pack2(v.z, v.w);
        *(uint2*)(nbb + (size_t)b * DB + j0 + p * 4) = u;
    }
}

// ---------------------------------------------------------------------------
// khq: hq = relu([nb | obs] @ W_bq^T + b_bq) -> hqb bf16. grid 128.
// ---------------------------------------------------------------------------
__global__ __launch_bounds__(256) void khq(
    const short* __restrict__ nbb, const float* __restrict__ obs_t,
    const short* __restrict__ Wbq_bf, const float* __restrict__ b_bq,
    short* __restrict__ hqb)
{
    __shared__ __align__(16) char smem[12288];
    const int q = blockIdx.x, tx = threadIdx.x;
    const int wv = tx >> 6, lane = tx & 63;
    const int b0 = (q >> 5) * 64, j0 = (q & 31) * 32;
    const int wm = wv & 1, wn = wv >> 1;
    const bf8_t* nb8 = (const bf8_t*)nbb;
    const bf8_t* Wq8 = (const bf8_t*)Wbq_bf;
    bf8_t* sA = (bf8_t*)smem;
    bf8_t* sB = sA + 512;
    f4_t acc[2];
    acc[0] = (f4_t)0.0f; acc[1] = (f4_t)0.0f;

    for (int kt = 0; kt < DB + DE; kt += 64) {
        #pragma unroll
        for (int i = 0; i < 2; ++i) {
            int c = tx + i * 256;
            int row = c >> 3, ch = c & 7, b = b0 + row;
            bf8_t v;
            if (kt < DB) {
                v = nb8[(size_t)b * 128 + (kt >> 3) + ch];
            } else {
                const float4* p4 = (const float4*)(obs_t + (size_t)b * DE + (kt - DB) + ch * 8);
                float4 f0 = p4[0], f1 = p4[1];
                v[0]=f2bf(f0.x); v[1]=f2bf(f0.y); v[2]=f2bf(f0.z); v[3]=f2bf(f0.w);
                v[4]=f2bf(f1.x); v[5]=f2bf(f1.y); v[6]=f2bf(f1.z); v[7]=f2bf(f1.w);
            }
            sA[row * 8 + (ch ^ (row & 7))] = v;
        }
        {
            int row = tx >> 3, ch = tx & 7;
            sB[row * 8 + (ch ^ (row & 7))] = Wq8[(size_t)(j0 + row) * 256 + (kt >> 3) + ch];
        }
        __syncthreads();
        #pragma unroll
        for (int ks = 0; ks < 2; ++ks) {
            int ch = ks * 4 + (lane >> 4);
            bf8_t a[2], b;
            #pragma unroll
            for (int mi = 0; mi < 2; ++mi) {
                int row = wm * 32 + mi * 16 + (lane & 15);
                a[mi] = sA[row * 8 + (ch ^ (row & 7))];
            }
            {
                int row = wn * 16 + (lane & 15);
                b = sB[row * 8 + (ch ^ (row & 7))];
            }
            acc[0] = MFMA16(a[0], b, acc[0]);
            acc[1] = MFMA16(a[1], b, acc[1]);
        }
        __syncthreads();
    }
    float* ebuf = (float*)smem;          // [64][32]
    #pragma unroll
    for (int mi = 0; mi < 2; ++mi)
        #pragma unroll
        for (int r = 0; r < 4; ++r) {
            int row = wm * 32 + mi * 16 + (lane >> 4) * 4 + r;
            int col = wn * 16 + (lane & 15);
            ebuf[row * 32 + col] = fmaxf(acc[mi][r] + b_bq[j0 + col], 0.0f);
        }
    __syncthreads();
    {
        int bl = tx >> 2, p = tx & 3;
        float* src = ebuf + bl * 32 + p * 8;
        short* dst = hqb + (size_t)(b0 + bl) * DH + j0 + p * 8;
        #pragma unroll
        for (int q2 = 0; q2 < 2; ++q2) {
            uint2 u; u.x = pack2(src[q2*4], src[q2*4+1]); u.y = pack2(src[q2*4+2], src[q2*4+3]);
            *(uint2*)(dst + q2 * 4) = u;
        }
    }
}

// ---------------------------------------------------------------------------
// kout: [mean|sd] = A @ W^T + b; softplus; sample. A bf16 [rows][1024].
// grid (8 i-tiles, rows/64 b-tiles). Used for posterior (in-loop, rows=256)
// and prior (post-loop chunks, rows=4096).
// ---------------------------------------------------------------------------
__global__ __launch_bounds__(256) void kout(
    const short* __restrict__ A_, const short* __restrict__ W_,
    const float* __restrict__ bias, const float* __restrict__ noise,
    float* __restrict__ om, float* __restrict__ osd, float* __restrict__ os)
{
    __shared__ __align__(16) char smem[12288];
    const int tx = threadIdx.x;
    const int wv = tx >> 6, lane = tx & 63;
    const int b0 = blockIdx.y * 64, i0 = blockIdx.x * 16;
    const int wm = wv & 1, wn = wv >> 1;
    const bf8_t* A8 = (const bf8_t*)A_;
    const bf8_t* W8 = (const bf8_t*)W_;
    bf8_t* sA = (bf8_t*)smem;
    bf8_t* sB = sA + 512;
    f4_t acc[2];
    acc[0] = (f4_t)0.0f; acc[1] = (f4_t)0.0f;

    for (int kt = 0; kt < DH; kt += 64) {
        #pragma unroll
        for (int i = 0; i < 2; ++i) {
            int c = tx + i * 256;
            int row = c >> 3, ch = c & 7;
            sA[row * 8 + (ch ^ (row & 7))] = A8[(size_t)(b0 + row) * 128 + (kt >> 3) + ch];
        }
        {
            int row = tx >> 3, ch = tx & 7;   // 32 rows: 16 mean + 16 sd
            int wr = (row < 16) ? (i0 + row) : (128 + i0 + (row - 16));
            sB[row * 8 + (ch ^ (row & 7))] = W8[(size_t)wr * 128 + (kt >> 3) + ch];
        }
        __syncthreads();
        #pragma unroll
        for (int ks = 0; ks < 2; ++ks) {
            int ch = ks * 4 + (lane >> 4);
            bf8_t a[2], b;
            #pragma unroll
            for (int mi = 0; mi < 2; ++mi) {
                int row = wm * 32 + mi * 16 + (lane & 15);
                a[mi] = sA[row * 8 + (ch ^ (row & 7))];
            }
            {
                int row = wn * 16 + (lane & 15);
                b = sB[row * 8 + (ch ^ (row & 7))];
            }
            acc[0] = MFMA16(a[0], b, acc[0]);
            acc[1] = MFMA16(a[1], b, acc[1]);
        }
        __syncthreads();
    }
    float* ebuf = (float*)smem;          // [64][32]
    #pragma unroll
    for (int mi = 0; mi < 2; ++mi)
        #pragma unroll
        for (int r = 0; r < 4; ++r) {
            int row = wm * 32 + mi * 16 + (lane >> 4) * 4 + r;
            int col = wn * 16 + (lane & 15);
            ebuf[row * 32 + col] = acc[mi][r];
        }
    __syncthreads();
    {
        int bl = tx >> 2, p = tx & 3;
        int b = b0 + bl;
        float4 vm, vs, vx;
        #pragma unroll
        for (int k = 0; k < 4; ++k) {
            int i = p * 4 + k;
            float m_ = ebuf[bl * 32 + i] + bias[i0 + i];
            float sraw = ebuf[bl * 32 + 16 + i] + bias[128 + i0 + i];
            float sd = log1pf(__expf(-fabsf(sraw))) + fmaxf(sraw, 0.0f) + MIN_STD;
            float n_ = noise[(size_t)b * DS + i0 + i];
            ((float*)&vm)[k] = m_;
            ((float*)&vs)[k] = sd;
            ((float*)&vx)[k] = fmaf(sd, n_, m_);
        }
        size_t off = (size_t)b * DS + i0 + p * 4;
        *(float4*)(om + off)  = vm;
        *(float4*)(osd + off) = vs;
        *(float4*)(os + off)  = vx;
    }
}

// ---------------------------------------------------------------------------
// khp: hp = relu(beliefs @ W_bp^T + b_bp) for a 4096-row chunk -> hp_bf.
// grid (16 j-tiles, 64 m-tiles). A staged from f32 with inline convert.
// ---------------------------------------------------------------------------
__global__ __launch_bounds__(256) void khp(
    const float* __restrict__ belA, const short* __restrict__ Wbp_bf,
    const float* __restrict__ b_bp, short* __restrict__ hp_bf)
{
    __shared__ __align__(16) char smem[16384];
    const int tx = threadIdx.x;
    const int wv = tx >> 6, lane = tx & 63;
    const int b0 = blockIdx.y * 64, j0 = blockIdx.x * 64;
    const int wm = wv & 1, wn = wv >> 1;
    const bf8_t* Wp8 = (const bf8_t*)Wbp_bf;
    bf8_t* sA = (bf8_t*)smem;
    bf8_t* sB = sA + 512;
    f4_t acc[2][2];
    acc[0][0] = (f4_t)0.0f; acc[0][1] = (f4_t)0.0f;
    acc[1][0] = (f4_t)0.0f; acc[1][1] = (f4_t)0.0f;

    for (int kt = 0; kt < DB; kt += 64) {
        #pragma unroll
        for (int i = 0; i < 2; ++i) {
            int c = tx + i * 256;
            int row = c >> 3, ch = c & 7;
            const float4* p4 = (const float4*)(belA + (size_t)(b0 + row) * DB + kt + ch * 8);
            float4 f0 = p4[0], f1 = p4[1];
            bf8_t v;
            v[0]=f2bf(f0.x); v[1]=f2bf(f0.y); v[2]=f2bf(f0.z); v[3]=f2bf(f0.w);
            v[4]=f2bf(f1.x); v[5]=f2bf(f1.y); v[6]=f2bf(f1.z); v[7]=f2bf(f1.w);
            sA[row * 8 + (ch ^ (row & 7))] = v;
            sB[row * 8 + (ch ^ (row & 7))] = Wp8[(size_t)(j0 + row) * 128 + (kt >> 3) + ch];
        }
        __syncthreads();
        #pragma unroll
        for (int ks = 0; ks < 2; ++ks) {
            int ch = ks * 4 + (lane >> 4);
            bf8_t a[2], b[2];
            #pragma unroll
            for (int mi = 0; mi < 2; ++mi) {
                int row = wm * 32 + mi * 16 + (lane & 15);
                a[mi] = sA[row * 8 + (ch ^ (row & 7))];
            }
            #pragma unroll
            for (int ni = 0; ni < 2; ++ni) {
                int row = wn * 32 + ni * 16 + (lane & 15);
                b[ni] = sB[row * 8 + (ch ^ (row & 7))];
            }
            #pragma unroll
            for (int mi = 0; mi < 2; ++mi)
                #pragma unroll
                for (int ni = 0; ni < 2; ++ni)
                    acc[mi][ni] = MFMA16(a[mi], b[ni], acc[mi][ni]);
        }
        __syncthreads();
    }
    float* ebuf = (float*)smem;          // [64][64]
    #pragma unroll
    for (int mi = 0; mi < 2; ++mi)
        #pragma unroll
        for (int ni = 0; ni < 2; ++ni)
            #pragma unroll
            for (int r = 0; r < 4; ++r) {
                int row = wm * 32 + mi * 16 + (lane >> 4) * 4 + r;
                int col = wn * 32 + ni * 16 + (lane & 15);
                ebuf[row * 64 + col] = fmaxf(acc[mi][ni][r] + b_bp[j0 + col], 0.0f);
            }
    __syncthreads();
    {
        int bl = tx >> 2, p = tx & 3;
        float* src = ebuf + bl * 64 + p * 16;
        short* dst = hp_bf + (size_t)(b0 + bl) * DH + j0 + p * 16;
        #pragma unroll
        for (int q = 0; q < 4; ++q) {
            uint2 u; u.x = pack2(src[q*4], src[q*4+1]); u.y = pack2(src[q*4+2], src[q*4+3]);
            *(uint2*)(dst + q * 4) = u;
        }
    }
}

// ---------------------------------------------------------------------------
extern "C" void kernel_launch(void* const* d_in, const int* in_sizes, int n_in,
                              void* d_out, int out_size, void* d_ws, size_t ws_size,
                              hipStream_t stream)
{
    const float* prev_state   = (const float*)d_in[0];
    const float* actions      = (const float*)d_in[1];
    const float* prev_belief  = (const float*)d_in[2];
    const float* observations = (const float*)d_in[3];
    const float* nonterm      = (const float*)d_in[4];
    const float* prior_noise  = (const float*)d_in[5];
    const float* post_noise   = (const float*)d_in[6];
    const float* W_sa = (const float*)d_in[7];
    const float* b_sa = (const float*)d_in[8];
    const float* W_ih = (const float*)d_in[9];
    const float* W_hh = (const float*)d_in[10];
    const float* b_ih = (const float*)d_in[11];
    const float* b_hh = (const float*)d_in[12];
    const float* W_bp = (const float*)d_in[13];
    const float* b_bp = (const float*)d_in[14];
    const float* W_sp = (const float*)d_in[15];
    const float* b_sp = (const float*)d_in[16];
    const float* W_bq = (const float*)d_in[17];
    const float* b_bq = (const float*)d_in[18];
    const float* W_sq = (const float*)d_in[19];
    const float* b_sq = (const float*)d_in[20];

    float* out      = (float*)d_out;
    float* beliefs  = out;
    float* o_ps  = out + OUT_PS;
    float* o_pm  = out + OUT_PM;
    float* o_psd = out + OUT_PSD;
    float* o_qs  = out + OUT_QS;
    float* o_qm  = out + OUT_QM;
    float* o_qsd = out + OUT_QSD;

    // workspace (shorts)
    short* w = (short*)d_ws;
    short* Wih_bf = w;
    short* Whh_bf = Wih_bf + (size_t)3072 * 1024;
    short* Wbp_bf = Whh_bf + (size_t)3072 * 1024;
    short* Wbq_bf = Wbp_bf + (size_t)1024 * 1024;
    short* Wsp_bf = Wbq_bf + (size_t)1024 * 2048;
    short* Wsq_bf = Wsp_bf + (size_t)256 * 1024;
    short* Ax     = Wsq_bf + (size_t)256 * 1024;    // [256][1024]
    short* nbb    = Ax     + (size_t)NB * DB;       // [256][1024]
    short* hqb    = nbb    + (size_t)NB * DB;       // [256][1024]
    short* hp_bf  = hqb    + (size_t)NB * DH;       // [4096][1024] chunk

    auto cvt = [&](const float* s, short* d, size_t n) {
        int n8 = (int)(n / 8);
        k_cvt<<<(n8 + 255) / 256, 256, 0, stream>>>(s, d, n8);
    };
    cvt(W_ih, Wih_bf, (size_t)3072 * 1024);
    cvt(W_hh, Whh_bf, (size_t)3072 * 1024);
    cvt(W_bp, Wbp_bf, (size_t)1024 * 1024);
    cvt(W_bq, Wbq_bf, (size_t)1024 * 2048);
    cvt(W_sp, Wsp_bf, (size_t)256 * 1024);
    cvt(W_sq, Wsq_bf, (size_t)256 * 1024);

    // serial recurrence: only the posterior path
    for (int t = 0; t < NT; ++t) {
        const float* ntp = (t == 0) ? nullptr : nonterm + (size_t)(t - 1) * NB;
        const float* st  = (t == 0) ? prev_state  : o_qs + (size_t)(t - 1) * NB * DS;
        const float* bel = (t == 0) ? prev_belief : beliefs + (size_t)(t - 1) * NB * DB;

        kx<<<256, 256, 0, stream>>>(
            st, actions + (size_t)t * NB * DA, ntp, W_sa, b_sa, Ax);

        kgru<<<256, 256, 0, stream>>>(
            Ax, bel, ntp, Wih_bf, Whh_bf, b_ih, b_hh,
            beliefs + (size_t)t * NB * DB, nbb);

        khq<<<128, 256, 0, stream>>>(
            nbb, observations + (size_t)t * NB * DE, Wbq_bf, b_bq, hqb);

        kout<<<dim3(8, 4), 256, 0, stream>>>(
            hqb, Wsq_bf, b_sq, post_noise + (size_t)t * NB * DS,
            o_qm + (size_t)t * NB * DS, o_qsd + (size_t)t * NB * DS,
            o_qs + (size_t)t * NB * DS);
    }

    // prior head: batched over all t, 4 chunks of 16 steps (4096 rows)
    for (int c = 0; c < 4; ++c) {
        const size_t r0 = (size_t)c * 4096;
        khp<<<dim3(16, 64), 256, 0, stream>>>(
            beliefs + r0 * DB, Wbp_bf, b_bp, hp_bf);
        kout<<<dim3(8, 64), 256, 0, stream>>>(
            hp_bf, Wsp_bf, b_sp, prior_noise + r0 * DS,
            o_pm + r0 * DS, o_psd + r0 * DS, o_ps + r0 * DS);
    }
}

// Round 5
// 4565.478 us; speedup vs baseline: 3.2366x; 1.2357x over previous
//
#include <hip/hip_runtime.h>
#include <math.h>

constexpr int NB = 256, NT = 64, DS = 128, DA = 32, DB = 1024, DH = 1024, DE = 1024;
constexpr float MIN_STD = 0.1f;

constexpr size_t OUT_PS  = (size_t)NT * NB * DB;
constexpr size_t OUT_PM  = OUT_PS  + (size_t)NT * NB * DS;
constexpr size_t OUT_PSD = OUT_PM  + (size_t)NT * NB * DS;
constexpr size_t OUT_QS  = OUT_PSD + (size_t)NT * NB * DS;
constexpr size_t OUT_QM  = OUT_QS  + (size_t)NT * NB * DS;
constexpr size_t OUT_QSD = OUT_QM  + (size_t)NT * NB * DS;

typedef __attribute__((ext_vector_type(8))) short bf8_t;
typedef __attribute__((ext_vector_type(4))) float f4_t;
#define MFMA16(a, b, c) __builtin_amdgcn_mfma_f32_16x16x32_bf16((a), (b), (c), 0, 0, 0)

__device__ __forceinline__ short f2bf(float f) {
    union { float f; unsigned u; } v; v.f = f;
    unsigned r = v.u + 0x7FFF + ((v.u >> 16) & 1);
    return (short)(r >> 16);
}
__device__ __forceinline__ unsigned pack2(float a, float b) {
    return ((unsigned)(unsigned short)f2bf(a)) | (((unsigned)(unsigned short)f2bf(b)) << 16);
}
__device__ __forceinline__ float sigm(float x) { return 1.0f / (1.0f + __expf(-x)); }

// ---------------------------------------------------------------------------
// One-shot conversion of ALL weights to bf16 (+ frag-preswizzled Wsq/Wsa).
// Chunk ranges (8 f32 each):
//  Wih[0,393216) Whh[..786432) Wbp[..917504) Wbq[..1179648) Wsp[..1212416)
//  Wsq[..1245184) Wsq_sw[..1277952) Wsa_sw[..1298432)
// ---------------------------------------------------------------------------
__global__ __launch_bounds__(256) void k_cvt_all(
    const float* __restrict__ Wih, const float* __restrict__ Whh,
    const float* __restrict__ Wbp, const float* __restrict__ Wbq,
    const float* __restrict__ Wsp, const float* __restrict__ Wsq,
    const float* __restrict__ Wsa,
    short* dWih, short* dWhh, short* dWbp, short* dWbq,
    short* dWsp, short* dWsq, short* dWsqsw, short* dWsasw)
{
    int i = blockIdx.x * 256 + threadIdx.x;
    const float* src; short* dst; int lo; bool sw = false; int swNCH = 0;
    if      (i <  393216) { src = Wih; dst = dWih; lo = 0; }
    else if (i <  786432) { src = Whh; dst = dWhh; lo = 393216; }
    else if (i <  917504) { src = Wbp; dst = dWbp; lo = 786432; }
    else if (i < 1179648) { src = Wbq; dst = dWbq; lo = 917504; }
    else if (i < 1212416) { src = Wsp; dst = dWsp; lo = 1179648; }
    else if (i < 1245184) { src = Wsq; dst = dWsq; lo = 1212416; }
    else if (i < 1277952) { src = Wsq; dst = dWsqsw; lo = 1245184; sw = true; swNCH = 128; }
    else if (i < 1298432) { src = Wsa; dst = dWsasw; lo = 1277952; sw = true; swNCH = 20; }
    else return;
    int il = i - lo;
    const float4* s4 = (const float4*)src;
    float4 a = s4[il * 2], b = s4[il * 2 + 1];
    bf8_t v;
    v[0]=f2bf(a.x); v[1]=f2bf(a.y); v[2]=f2bf(a.z); v[3]=f2bf(a.w);
    v[4]=f2bf(b.x); v[5]=f2bf(b.y); v[6]=f2bf(b.z); v[7]=f2bf(b.w);
    if (!sw) ((bf8_t*)dst)[il] = v;
    else {
        int row = il / swNCH, ch = il % swNCH;
        ((bf8_t*)dst)[((row >> 4) * swNCH + ch) * 16 + (row & 15)] = v;
    }
}

// ---------------------------------------------------------------------------
// kmega (slot 1): per block = 16 batch rows x 64 gate-cols.
//   t>0: qs[t-1] = sample(hq[t-1] @ Wsq^T + b_sq)  (jt==0 writes outputs)
//   [s|a] -> x = relu(.@W_sa^T + b_sa)  (inline MFMA, preswizzled B)
//   GRU: gi = x@Wih^T, gh = (bel*nt)@Whh^T, gate math -> beliefs[t], nbb
// grid 256 = 16 bgrp x 16 jt, block 512 (8 waves).
// ---------------------------------------------------------------------------
__global__ __launch_bounds__(512) void kmega(
    int t,
    const float* __restrict__ prev_state, const float* __restrict__ actions_t,
    const float* __restrict__ nonterm, const float* __restrict__ post_noise,
    const short* __restrict__ hqb,
    const short* __restrict__ Wsq_sw, const float* __restrict__ b_sq,
    const short* __restrict__ Wsa_sw, const float* __restrict__ b_sa,
    const short* __restrict__ Wih_bf, const short* __restrict__ Whh_bf,
    const float* __restrict__ b_ih, const float* __restrict__ b_hh,
    const float* __restrict__ belp,
    float* __restrict__ bel_out, short* __restrict__ nbb,
    float* __restrict__ o_qm, float* __restrict__ o_qsd, float* __restrict__ o_qs)
{
    // LDS: R1 32768 | SA 5376 | SAH 2048 | SBW 49152  (total 89344)
    __shared__ __align__(16) char smem[89344];
    bf8_t* R1   = (bf8_t*)smem;                 // hq-stage / qex / xfull
    float* qex  = (float*)smem;                 // [16][257]
    short* xf   = (short*)smem;                 // [16][1024] swizzled chunks
    short* saS  = (short*)(smem + 32768);       // [16][168]
    bf8_t* sa8  = (bf8_t*)(smem + 32768);       // [16][21]
    bf8_t* sAh  = (bf8_t*)(smem + 38144);       // [16][8]
    bf8_t* sBw  = (bf8_t*)(smem + 40192);       // [6][64][8]
    float* exg  = (float*)(smem + 40192);       // [3][16][64] (after main loop)
    float* exn  = exg + 3 * 16 * 64;            // [16][64]

    const int tx = threadIdx.x, bid = blockIdx.x;
    const int wv = tx >> 6, lane = tx & 63;
    const int bgrp = bid >> 4, jt = bid & 15;
    const int b0 = bgrp * 16, j0 = jt * 64;

    // ---------------- Phase Q: qs[t-1] + s-part of [s|a] ----------------
    if (t > 0) {
        const bf8_t* hq8 = (const bf8_t*)hqb;
        #pragma unroll
        for (int i = 0; i < 4; ++i) {
            int c = tx + i * 512;              // 2048 = 16 rows x 128 chunks
            int row = c >> 7, ch = c & 127;
            R1[row * 128 + ((ch & ~7) | ((ch & 7) ^ (row & 7)))] =
                hq8[(size_t)(b0 + row) * 128 + ch];
        }
        __syncthreads();
        f4_t qacc[2]; qacc[0] = (f4_t)0.0f; qacc[1] = (f4_t)0.0f;
        for (int ks = 0; ks < 32; ++ks) {
            int ch = ks * 4 + (lane >> 4);
            int ar = lane & 15;
            bf8_t a = R1[ar * 128 + ((ch & ~7) | ((ch & 7) ^ (ar & 7)))];
            #pragma unroll
            for (int ni = 0; ni < 2; ++ni) {
                int tile = wv * 2 + ni;
                bf8_t bfr = *(const bf8_t*)(Wsq_sw + ((size_t)(tile * 128 + ch)) * 128 + (lane & 15) * 8);
                qacc[ni] = MFMA16(a, bfr, qacc[ni]);
            }
        }
        __syncthreads();
        #pragma unroll
        for (int ni = 0; ni < 2; ++ni)
            #pragma unroll
            for (int r = 0; r < 4; ++r) {
                int row = (lane >> 4) * 4 + r;
                int col = wv * 32 + ni * 16 + (lane & 15);
                qex[row * 257 + col] = qacc[ni][r];
            }
        __syncthreads();
        #pragma unroll
        for (int i = 0; i < 4; ++i) {
            int e = tx + i * 512;              // 2048 = 16 x 128
            int row = e >> 7, col = e & 127;
            int b = b0 + row;
            float m  = qex[row * 257 + col] + b_sq[col];
            float sr = qex[row * 257 + 128 + col] + b_sq[128 + col];
            float sd = log1pf(__expf(-fabsf(sr))) + fmaxf(sr, 0.0f) + MIN_STD;
            float n_ = post_noise[((size_t)(t - 1) * NB + b) * DS + col];
            float qs = fmaf(sd, n_, m);
            if (jt == 0) {
                size_t off = ((size_t)(t - 1) * NB + b) * DS + col;
                o_qm[off] = m; o_qsd[off] = sd; o_qs[off] = qs;
            }
            float ntv = nonterm[(size_t)(t - 1) * NB + b];
            saS[row * 168 + col] = f2bf(qs * ntv);
        }
    } else {
        #pragma unroll
        for (int i = 0; i < 4; ++i) {
            int e = tx + i * 512;
            int row = e >> 7, col = e & 127;
            saS[row * 168 + col] = f2bf(prev_state[(size_t)(b0 + row) * DS + col]);
        }
    }
    {   // a-part: 16 x 32
        int row = tx >> 5, ac = tx & 31;
        saS[row * 168 + 128 + ac] = f2bf(actions_t[(size_t)(b0 + row) * DA + ac]);
    }
    __syncthreads();

    // ---------------- Phase X: x = relu([s|a] @ W_sa^T + b_sa) ----------
    {
        f4_t xacc[8];
        #pragma unroll
        for (int i = 0; i < 8; ++i) xacc[i] = (f4_t)0.0f;
        #pragma unroll
        for (int ks = 0; ks < 5; ++ks) {
            int ch = ks * 4 + (lane >> 4);
            bf8_t a = sa8[(lane & 15) * 21 + ch];
            #pragma unroll
            for (int ni = 0; ni < 8; ++ni) {
                int tile = wv * 8 + ni;
                bf8_t bfr = *(const bf8_t*)(Wsa_sw + ((size_t)(tile * 20 + ch)) * 128 + (lane & 15) * 8);
                xacc[ni] = MFMA16(a, bfr, xacc[ni]);
            }
        }
        #pragma unroll
        for (int ni = 0; ni < 8; ++ni) {
            int col = wv * 128 + ni * 16 + (lane & 15);
            float bj = b_sa[col];
            int chunk = col >> 3, el = col & 7;
            #pragma unroll
            for (int r = 0; r < 4; ++r) {
                int row = (lane >> 4) * 4 + r;
                int swch = (chunk & ~7) | ((chunk & 7) ^ (row & 7));
                xf[row * 1024 + swch * 8 + el] = f2bf(fmaxf(xacc[ni][r] + bj, 0.0f));
            }
        }
    }
    __syncthreads();

    // ---------------- Phase G: GRU ----------------
    const int wg = wv & 1, wn = wv >> 1;        // wn 0..3
    f4_t acc[3];
    acc[0] = (f4_t)0.0f; acc[1] = (f4_t)0.0f; acc[2] = (f4_t)0.0f;
    const bf8_t* Wi8 = (const bf8_t*)Wih_bf;
    const bf8_t* Wh8 = (const bf8_t*)Whh_bf;

    for (int kt = 0; kt < DB; kt += 64) {
        if (tx < 128) {
            int row = tx >> 3, ch = tx & 7;
            int b = b0 + row;
            const float4* p4 = (const float4*)(belp + (size_t)b * DB + kt + ch * 8);
            float4 f0 = p4[0], f1 = p4[1];
            float ntv = (t == 0) ? 1.0f : nonterm[(size_t)(t - 1) * NB + b];
            bf8_t v;
            v[0]=f2bf(f0.x*ntv); v[1]=f2bf(f0.y*ntv); v[2]=f2bf(f0.z*ntv); v[3]=f2bf(f0.w*ntv);
            v[4]=f2bf(f1.x*ntv); v[5]=f2bf(f1.y*ntv); v[6]=f2bf(f1.z*ntv); v[7]=f2bf(f1.w*ntv);
            sAh[row * 8 + (ch ^ (row & 7))] = v;
        }
        #pragma unroll
        for (int i = 0; i < 6; ++i) {
            int c = tx + i * 512;              // 3072 = 6 x 64 x 8
            int g = c >> 9, r = (c >> 3) & 63, ch = c & 7;
            const bf8_t* W = (g < 3) ? Wi8 : Wh8;
            int gm = (g >= 3) ? g - 3 : g;
            sBw[(g * 64 + r) * 8 + (ch ^ (r & 7))] =
                W[((size_t)gm * DB + j0 + r) * 128 + (kt >> 3) + ch];
        }
        __syncthreads();
        #pragma unroll
        for (int ks = 0; ks < 2; ++ks) {
            int chl = ks * 4 + (lane >> 4);
            int ar = lane & 15;
            bf8_t a;
            if (wg) a = sAh[ar * 8 + (chl ^ (ar & 7))];
            else    a = ((bf8_t*)smem)[ar * 128 + (kt >> 3) + (chl ^ (ar & 7))];
            #pragma unroll
            for (int g = 0; g < 3; ++g) {
                int r = wn * 16 + (lane & 15);
                bf8_t bfr = sBw[((wg * 3 + g) * 64 + r) * 8 + (chl ^ (r & 7))];
                acc[g] = MFMA16(a, bfr, acc[g]);
            }
        }
        __syncthreads();
    }

    if (wg == 1) {
        #pragma unroll
        for (int g = 0; g < 3; ++g)
            #pragma unroll
            for (int r = 0; r < 4; ++r) {
                int row = (lane >> 4) * 4 + r;
                exg[(g * 16 + row) * 64 + wn * 16 + (lane & 15)] = acc[g][r];
            }
    }
    __syncthreads();
    if (wg == 0) {
        int jl = wn * 16 + (lane & 15);
        int j = j0 + jl;
        float bir = b_ih[j], biz = b_ih[DB + j], bin = b_ih[2 * DB + j];
        float bhr = b_hh[j], bhz = b_hh[DB + j], bhn = b_hh[2 * DB + j];
        #pragma unroll
        for (int r = 0; r < 4; ++r) {
            int row = (lane >> 4) * 4 + r;
            int b = b0 + row;
            float ntv = (t == 0) ? 1.0f : nonterm[(size_t)(t - 1) * NB + b];
            float h = belp[(size_t)b * DB + j] * ntv;
            float rr = sigm(acc[0][r] + bir + exg[(0 * 16 + row) * 64 + jl] + bhr);
            float zz = sigm(acc[1][r] + biz + exg[(1 * 16 + row) * 64 + jl] + bhz);
            float nn = tanhf(acc[2][r] + bin + rr * (exg[(2 * 16 + row) * 64 + jl] + bhn));
            exn[row * 64 + jl] = (1.0f - zz) * nn + zz * h;
        }
    }
    __syncthreads();
    {
        #pragma unroll
        for (int i = 0; i < 2; ++i) {
            int e = tx + i * 512;              // 1024 = 16 x 64
            int row = e >> 6, col = e & 63;
            bel_out[(size_t)(b0 + row) * DB + j0 + col] = exn[row * 64 + col];
        }
        int row = tx >> 5, cp = tx & 31;       // 512 u32 = 16 x 32 pairs
        unsigned pv = pack2(exn[row * 64 + cp * 2], exn[row * 64 + cp * 2 + 1]);
        *(unsigned*)(nbb + (size_t)(b0 + row) * DB + j0 + cp * 2) = pv;
    }
}

// ---------------------------------------------------------------------------
// khq (slot 2): hq = relu([nb | obs] @ W_bq^T + b_bq). grid 128. (R4 verbatim)
// ---------------------------------------------------------------------------
__global__ __launch_bounds__(256) void khq(
    const short* __restrict__ nbb, const float* __restrict__ obs_t,
    const short* __restrict__ Wbq_bf, const float* __restrict__ b_bq,
    short* __restrict__ hqb)
{
    __shared__ __align__(16) char smem[12288];
    const int q = blockIdx.x, tx = threadIdx.x;
    const int wv = tx >> 6, lane = tx & 63;
    const int b0 = (q >> 5) * 64, j0 = (q & 31) * 32;
    const int wm = wv & 1, wn = wv >> 1;
    const bf8_t* nb8 = (const bf8_t*)nbb;
    const bf8_t* Wq8 = (const bf8_t*)Wbq_bf;
    bf8_t* sA = (bf8_t*)smem;
    bf8_t* sB = sA + 512;
    f4_t acc[2];
    acc[0] = (f4_t)0.0f; acc[1] = (f4_t)0.0f;

    for (int kt = 0; kt < DB + DE; kt += 64) {
        #pragma unroll
        for (int i = 0; i < 2; ++i) {
            int c = tx + i * 256;
            int row = c >> 3, ch = c & 7, b = b0 + row;
            bf8_t v;
            if (kt < DB) {
                v = nb8[(size_t)b * 128 + (kt >> 3) + ch];
            } else {
                const float4* p4 = (const float4*)(obs_t + (size_t)b * DE + (kt - DB) + ch * 8);
                float4 f0 = p4[0], f1 = p4[1];
                v[0]=f2bf(f0.x); v[1]=f2bf(f0.y); v[2]=f2bf(f0.z); v[3]=f2bf(f0.w);
                v[4]=f2bf(f1.x); v[5]=f2bf(f1.y); v[6]=f2bf(f1.z); v[7]=f2bf(f1.w);
            }
            sA[row * 8 + (ch ^ (row & 7))] = v;
        }
        {
            int row = tx >> 3, ch = tx & 7;
            sB[row * 8 + (ch ^ (row & 7))] = Wq8[(size_t)(j0 + row) * 256 + (kt >> 3) + ch];
        }
        __syncthreads();
        #pragma unroll
        for (int ks = 0; ks < 2; ++ks) {
            int ch = ks * 4 + (lane >> 4);
            bf8_t a[2], b;
            #pragma unroll
            for (int mi = 0; mi < 2; ++mi) {
                int row = wm * 32 + mi * 16 + (lane & 15);
                a[mi] = sA[row * 8 + (ch ^ (row & 7))];
            }
            {
                int row = wn * 16 + (lane & 15);
                b = sB[row * 8 + (ch ^ (row & 7))];
            }
            acc[0] = MFMA16(a[0], b, acc[0]);
            acc[1] = MFMA16(a[1], b, acc[1]);
        }
        __syncthreads();
    }
    float* ebuf = (float*)smem;
    #pragma unroll
    for (int mi = 0; mi < 2; ++mi)
        #pragma unroll
        for (int r = 0; r < 4; ++r) {
            int row = wm * 32 + mi * 16 + (lane >> 4) * 4 + r;
            int col = wn * 16 + (lane & 15);
            ebuf[row * 32 + col] = fmaxf(acc[mi][r] + b_bq[j0 + col], 0.0f);
        }
    __syncthreads();
    {
        int bl = tx >> 2, p = tx & 3;
        float* src = ebuf + bl * 32 + p * 8;
        short* dst = hqb + (size_t)(b0 + bl) * DH + j0 + p * 8;
        #pragma unroll
        for (int q2 = 0; q2 < 2; ++q2) {
            uint2 u; u.x = pack2(src[q2*4], src[q2*4+1]); u.y = pack2(src[q2*4+2], src[q2*4+3]);
            *(uint2*)(dst + q2 * 4) = u;
        }
    }
}

// ---------------------------------------------------------------------------
// kout: [mean|sd] = A @ W^T + b; softplus; sample. (R4 verbatim)
// ---------------------------------------------------------------------------
__global__ __launch_bounds__(256) void kout(
    const short* __restrict__ A_, const short* __restrict__ W_,
    const float* __restrict__ bias, const float* __restrict__ noise,
    float* __restrict__ om, float* __restrict__ osd, float* __restrict__ os)
{
    __shared__ __align__(16) char smem[12288];
    const int tx = threadIdx.x;
    const int wv = tx >> 6, lane = tx & 63;
    const int b0 = blockIdx.y * 64, i0 = blockIdx.x * 16;
    const int wm = wv & 1, wn = wv >> 1;
    const bf8_t* A8 = (const bf8_t*)A_;
    const bf8_t* W8 = (const bf8_t*)W_;
    bf8_t* sA = (bf8_t*)smem;
    bf8_t* sB = sA + 512;
    f4_t acc[2];
    acc[0] = (f4_t)0.0f; acc[1] = (f4_t)0.0f;

    for (int kt = 0; kt < DH; kt += 64) {
        #pragma unroll
        for (int i = 0; i < 2; ++i) {
            int c = tx + i * 256;
            int row = c >> 3, ch = c & 7;
            sA[row * 8 + (ch ^ (row & 7))] = A8[(size_t)(b0 + row) * 128 + (kt >> 3) + ch];
        }
        {
            int row = tx >> 3, ch = tx & 7;
            int wr = (row < 16) ? (i0 + row) : (128 + i0 + (row - 16));
            sB[row * 8 + (ch ^ (row & 7))] = W8[(size_t)wr * 128 + (kt >> 3) + ch];
        }
        __syncthreads();
        #pragma unroll
        for (int ks = 0; ks < 2; ++ks) {
            int ch = ks * 4 + (lane >> 4);
            bf8_t a[2], b;
            #pragma unroll
            for (int mi = 0; mi < 2; ++mi) {
                int row = wm * 32 + mi * 16 + (lane & 15);
                a[mi] = sA[row * 8 + (ch ^ (row & 7))];
            }
            {
                int row = wn * 16 + (lane & 15);
                b = sB[row * 8 + (ch ^ (row & 7))];
            }
            acc[0] = MFMA16(a[0], b, acc[0]);
            acc[1] = MFMA16(a[1], b, acc[1]);
        }
        __syncthreads();
    }
    float* ebuf = (float*)smem;
    #pragma unroll
    for (int mi = 0; mi < 2; ++mi)
        #pragma unroll
        for (int r = 0; r < 4; ++r) {
            int row = wm * 32 + mi * 16 + (lane >> 4) * 4 + r;
            int col = wn * 16 + (lane & 15);
            ebuf[row * 32 + col] = acc[mi][r];
        }
    __syncthreads();
    {
        int bl = tx >> 2, p = tx & 3;
        int b = b0 + bl;
        float4 vm, vs, vx;
        #pragma unroll
        for (int k = 0; k < 4; ++k) {
            int i = p * 4 + k;
            float m_ = ebuf[bl * 32 + i] + bias[i0 + i];
            float sraw = ebuf[bl * 32 + 16 + i] + bias[128 + i0 + i];
            float sd = log1pf(__expf(-fabsf(sraw))) + fmaxf(sraw, 0.0f) + MIN_STD;
            float n_ = noise[(size_t)b * DS + i0 + i];
            ((float*)&vm)[k] = m_;
            ((float*)&vs)[k] = sd;
            ((float*)&vx)[k] = fmaf(sd, n_, m_);
        }
        size_t off = (size_t)b * DS + i0 + p * 4;
        *(float4*)(om + off)  = vm;
        *(float4*)(osd + off) = vs;
        *(float4*)(os + off)  = vx;
    }
}

// ---------------------------------------------------------------------------
// khp: hp = relu(beliefs @ W_bp^T + b_bp), 4096-row chunk. (R4 verbatim)
// ---------------------------------------------------------------------------
__global__ __launch_bounds__(256) void khp(
    const float* __restrict__ belA, const short* __restrict__ Wbp_bf,
    const float* __restrict__ b_bp, short* __restrict__ hp_bf)
{
    __shared__ __align__(16) char smem[16384];
    const int tx = threadIdx.x;
    const int wv = tx >> 6, lane = tx & 63;
    const int b0 = blockIdx.y * 64, j0 = blockIdx.x * 64;
    const int wm = wv & 1, wn = wv >> 1;
    const bf8_t* Wp8 = (const bf8_t*)Wbp_bf;
    bf8_t* sA = (bf8_t*)smem;
    bf8_t* sB = sA + 512;
    f4_t acc[2][2];
    acc[0][0] = (f4_t)0.0f; acc[0][1] = (f4_t)0.0f;
    acc[1][0] = (f4_t)0.0f; acc[1][1] = (f4_t)0.0f;

    for (int kt = 0; kt < DB; kt += 64) {
        #pragma unroll
        for (int i = 0; i < 2; ++i) {
            int c = tx + i * 256;
            int row = c >> 3, ch = c & 7;
            const float4* p4 = (const float4*)(belA + (size_t)(b0 + row) * DB + kt + ch * 8);
            float4 f0 = p4[0], f1 = p4[1];
            bf8_t v;
            v[0]=f2bf(f0.x); v[1]=f2bf(f0.y); v[2]=f2bf(f0.z); v[3]=f2bf(f0.w);
            v[4]=f2bf(f1.x); v[5]=f2bf(f1.y); v[6]=f2bf(f1.z); v[7]=f2bf(f1.w);
            sA[row * 8 + (ch ^ (row & 7))] = v;
            sB[row * 8 + (ch ^ (row & 7))] = Wp8[(size_t)(j0 + row) * 128 + (kt >> 3) + ch];
        }
        __syncthreads();
        #pragma unroll
        for (int ks = 0; ks < 2; ++ks) {
            int ch = ks * 4 + (lane >> 4);
            bf8_t a[2], b[2];
            #pragma unroll
            for (int mi = 0; mi < 2; ++mi) {
                int row = wm * 32 + mi * 16 + (lane & 15);
                a[mi] = sA[row * 8 + (ch ^ (row & 7))];
            }
            #pragma unroll
            for (int ni = 0; ni < 2; ++ni) {
                int row = wn * 32 + ni * 16 + (lane & 15);
                b[ni] = sB[row * 8 + (ch ^ (row & 7))];
            }
            #pragma unroll
            for (int mi = 0; mi < 2; ++mi)
                #pragma unroll
                for (int ni = 0; ni < 2; ++ni)
                    acc[mi][ni] = MFMA16(a[mi], b[ni], acc[mi][ni]);
        }
        __syncthreads();
    }
    float* ebuf = (float*)smem;
    #pragma unroll
    for (int mi = 0; mi < 2; ++mi)
        #pragma unroll
        for (int ni = 0; ni < 2; ++ni)
            #pragma unroll
            for (int r = 0; r < 4; ++r) {
                int row = wm * 32 + mi * 16 + (lane >> 4) * 4 + r;
                int col = wn * 32 + ni * 16 + (lane & 15);
                ebuf[row * 64 + col] = fmaxf(acc[mi][ni][r] + b_bp[j0 + col], 0.0f);
            }
    __syncthreads();
    {
        int bl = tx >> 2, p = tx & 3;
        float* src = ebuf + bl * 64 + p * 16;
        short* dst = hp_bf + (size_t)(b0 + bl) * DH + j0 + p * 16;
        #pragma unroll
        for (int q = 0; q < 4; ++q) {
            uint2 u; u.x = pack2(src[q*4], src[q*4+1]); u.y = pack2(src[q*4+2], src[q*4+3]);
            *(uint2*)(dst + q * 4) = u;
        }
    }
}

// ---------------------------------------------------------------------------
extern "C" void kernel_launch(void* const* d_in, const int* in_sizes, int n_in,
                              void* d_out, int out_size, void* d_ws, size_t ws_size,
                              hipStream_t stream)
{
    const float* prev_state   = (const float*)d_in[0];
    const float* actions      = (const float*)d_in[1];
    const float* prev_belief  = (const float*)d_in[2];
    const float* observations = (const float*)d_in[3];
    const float* nonterm      = (const float*)d_in[4];
    const float* prior_noise  = (const float*)d_in[5];
    const float* post_noise   = (const float*)d_in[6];
    const float* W_sa = (const float*)d_in[7];
    const float* b_sa = (const float*)d_in[8];
    const float* W_ih = (const float*)d_in[9];
    const float* W_hh = (const float*)d_in[10];
    const float* b_ih = (const float*)d_in[11];
    const float* b_hh = (const float*)d_in[12];
    const float* W_bp = (const float*)d_in[13];
    const float* b_bp = (const float*)d_in[14];
    const float* W_sp = (const float*)d_in[15];
    const float* b_sp = (const float*)d_in[16];
    const float* W_bq = (const float*)d_in[17];
    const float* b_bq = (const float*)d_in[18];
    const float* W_sq = (const float*)d_in[19];
    const float* b_sq = (const float*)d_in[20];

    float* out     = (float*)d_out;
    float* beliefs = out;
    float* o_ps  = out + OUT_PS;
    float* o_pm  = out + OUT_PM;
    float* o_psd = out + OUT_PSD;
    float* o_qs  = out + OUT_QS;
    float* o_qm  = out + OUT_QM;
    float* o_qsd = out + OUT_QSD;

    // workspace (shorts)
    short* w = (short*)d_ws;
    short* Wih_bf = w;                                   // 3145728
    short* Whh_bf = Wih_bf + (size_t)3145728;            // 3145728
    short* Wbp_bf = Whh_bf + (size_t)3145728;            // 1048576
    short* Wbq_bf = Wbp_bf + (size_t)1048576;            // 2097152
    short* Wsp_bf = Wbq_bf + (size_t)2097152;            // 262144
    short* Wsq_bf = Wsp_bf + (size_t)262144;             // 262144
    short* Wsq_sw = Wsq_bf + (size_t)262144;             // 262144
    short* Wsa_sw = Wsq_sw + (size_t)262144;             // 163840
    short* nbb    = Wsa_sw + (size_t)163840;             // 262144
    short* hqb    = nbb    + (size_t)262144;             // 262144
    short* hp_bf  = hqb    + (size_t)262144;             // 4194304

    k_cvt_all<<<5072, 256, 0, stream>>>(
        W_ih, W_hh, W_bp, W_bq, W_sp, W_sq, W_sa,
        Wih_bf, Whh_bf, Wbp_bf, Wbq_bf, Wsp_bf, Wsq_bf, Wsq_sw, Wsa_sw);

    for (int t = 0; t < NT; ++t) {
        const float* belp = (t == 0) ? prev_belief : beliefs + (size_t)(t - 1) * NB * DB;
        kmega<<<256, 512, 0, stream>>>(
            t, prev_state, actions + (size_t)t * NB * DA,
            nonterm, post_noise, hqb,
            Wsq_sw, b_sq, Wsa_sw, b_sa,
            Wih_bf, Whh_bf, b_ih, b_hh,
            belp, beliefs + (size_t)t * NB * DB, nbb,
            o_qm, o_qsd, o_qs);
        khq<<<128, 256, 0, stream>>>(
            nbb, observations + (size_t)t * NB * DE, Wbq_bf, b_bq, hqb);
    }

    // posterior outputs for final step
    kout<<<dim3(8, 4), 256, 0, stream>>>(
        hqb, Wsq_bf, b_sq, post_noise + (size_t)(NT - 1) * NB * DS,
        o_qm + (size_t)(NT - 1) * NB * DS, o_qsd + (size_t)(NT - 1) * NB * DS,
        o_qs + (size_t)(NT - 1) * NB * DS);

    // prior head: batched, 4 chunks of 4096 rows
    for (int c = 0; c < 4; ++c) {
        const size_t r0 = (size_t)c * 4096;
        khp<<<dim3(16, 64), 256, 0, stream>>>(
            beliefs + r0 * DB, Wbp_bf, b_bp, hp_bf);
        kout<<<dim3(8, 64), 256, 0, stream>>>(
            hp_bf, Wsp_bf, b_sp, prior_noise + r0 * DS,
            o_pm + r0 * DS, o_psd + r0 * DS, o_ps + r0 * DS);
    }
}